// Round 13
// baseline (334.350 us; speedup 1.0000x reference)
//
#include <hip/hip_runtime.h>

// ROI pooling 3D as one-hot MFMA GEMM (transposed): part[ch][seg] = sum_v feat[ch][v] * onehot[v][seg].
// R13 = R8 + distance-1 software pipeline (double-buffered A-payload + atlas ids, static indexing),
// counts moved to a separate deterministic histogram kernel to free the VGPRs that pay for it.
constexpr int CROP_D  = 91, CROP_H = 109, CROP_W = 91;
constexpr int NVOX    = CROP_D * CROP_H * CROP_W;     // 902629
constexpr int LINES   = CROP_D * CROP_H;              // 9919
constexpr int FEAT_W  = 96;
constexpr int FEAT_HW = 112 * 96;
constexpr int CSTRIDE = 96 * 112 * 96;                // per-(b,c) elements
constexpr int NTILE   = LINES * 3;                    // 29757 tiles of 32 voxels (exact)
constexpr int PSEG    = 96;                           // 95 segs + trash col
constexpr int BIN_SZ  = 128 * PSEG;                   // 12288 floats per partial [ch][seg]
constexpr int GRID    = 1024;                         // 4 blocks/CU
constexpr int NCHUNK  = 16;
constexpr int KPC     = GRID / NCHUNK;                // 64
constexpr int NCB     = 64;                           // count-histogram blocks
constexpr int OUT_N   = 2 * 94 * 64;
constexpr size_t P2_OFF  = (size_t)GRID * BIN_SZ * sizeof(float);
constexpr size_t CNT_OFF = P2_OFF + (size_t)NCHUNK * BIN_SZ * sizeof(float);
constexpr size_t WS_NEED = CNT_OFF + (size_t)NCB * PSEG * sizeof(int);

typedef __attribute__((ext_vector_type(8))) short bf16x8;
typedef __attribute__((ext_vector_type(4))) float f32x4;

__device__ inline unsigned int rne2(float a, float b) {   // 2x fp32 -> packed bf16 (RNE)
    unsigned int x = __float_as_uint(a), y = __float_as_uint(b);
    x = (x + 0x7FFFu + ((x >> 16) & 1u)) >> 16;
    y = (y + 0x7FFFu + ((y >> 16) & 1u)) & 0xFFFF0000u;
    return x | y;
}

struct TileBuf {                                       // 24 VGPR, all statically indexed
    float4 p00, p01, p10, p11;                         // A payload: 2 ch-subtiles x 8 floats
    int id[8];                                         // atlas ids for this lane's k-quarter
};

__device__ inline void load_tile(const float* __restrict__ fb0,
                                 const float* __restrict__ fb1,
                                 const int*   __restrict__ atlas,
                                 int t, int lq, TileBuf& b)
{
    const int line = t / 3, w0 = (t - line * 3) * 32;
    const int d = line / CROP_H, h = line - d * CROP_H;
    const int lb = d * FEAT_HW + h * FEAT_W + w0 + lq * 8;
    b.p00 = *(const float4*)(fb0 + lb);
    b.p01 = *(const float4*)(fb0 + lb + 4);
    b.p10 = *(const float4*)(fb1 + lb);
    b.p11 = *(const float4*)(fb1 + lb + 4);
    const int wq = w0 + lq * 8, ab = line * CROP_W + wq;
    #pragma unroll
    for (int j = 0; j < 8; ++j)
        b.id[j] = (wq + j < CROP_W) ? atlas[ab + j] : 95;   // guarded: never OOB
}

__device__ inline void compute_tile(const TileBuf& b, int l15, f32x4 acc[2][6])
{
    union { bf16x8 v; unsigned int u[4]; } A0, A1;
    A0.u[0] = rne2(b.p00.x, b.p00.y); A0.u[1] = rne2(b.p00.z, b.p00.w);
    A0.u[2] = rne2(b.p01.x, b.p01.y); A0.u[3] = rne2(b.p01.z, b.p01.w);
    A1.u[0] = rne2(b.p10.x, b.p10.y); A1.u[1] = rne2(b.p10.z, b.p10.w);
    A1.u[2] = rne2(b.p11.x, b.p11.y); A1.u[3] = rne2(b.p11.z, b.p11.w);
    #pragma unroll
    for (int sb = 0; sb < 6; ++sb) {                   // B one-hot: col=l15 seg, k=lq*8+j
        const int seg = sb * 16 + l15;
        union { bf16x8 v; unsigned int u[4]; } B;
        #pragma unroll
        for (int p = 0; p < 4; ++p) {
            const unsigned int lo = (b.id[2 * p]     == seg) ? 0x3F80u     : 0u;
            const unsigned int hi = (b.id[2 * p + 1] == seg) ? 0x3F800000u : 0u;
            B.u[p] = lo | hi;
        }
        acc[0][sb] = __builtin_amdgcn_mfma_f32_16x16x32_bf16(A0.v, B.v, acc[0][sb], 0, 0, 0);
        acc[1][sb] = __builtin_amdgcn_mfma_f32_16x16x32_bf16(A1.v, B.v, acc[1][sb], 0, 0, 0);
    }
}

__global__ __launch_bounds__(256) void zero_part(float* __restrict__ p)   // atomic-fallback only
{
    const int i = blockIdx.x * 256 + threadIdx.x;
    if (i < BIN_SZ) p[i] = 0.0f;
}

__global__ __launch_bounds__(256, 4) void seg_mfma(const float* __restrict__ feat,
                                                   const int*   __restrict__ atlas,
                                                   float* __restrict__ part,
                                                   int use_atomic)
{
    const int tid = threadIdx.x, wv = tid >> 6, lane = tid & 63;
    const int l15 = lane & 15, lq = lane >> 4;

    f32x4 acc[2][6];                                   // 48 VGPR
    #pragma unroll
    for (int s = 0; s < 6; ++s) {
        acc[0][s] = (f32x4){0.f, 0.f, 0.f, 0.f};
        acc[1][s] = (f32x4){0.f, 0.f, 0.f, 0.f};
    }

    const int base = NTILE / GRID, rem = NTILE % GRID; // 29, 61
    const int bx   = blockIdx.x;
    const int t0   = bx * base + (bx < rem ? bx : rem);
    const int t1   = t0 + base + (bx < rem ? 1 : 0);

    const float* fb0 = feat + (size_t)(wv * 32 + l15) * CSTRIDE;        // a=0 subtile
    const float* fb1 = feat + (size_t)(wv * 32 + 16 + l15) * CSTRIDE;   // a=1 subtile

    TileBuf bufA, bufB;                                // distance-1 pipeline, static buffers
    load_tile(fb0, fb1, atlas, t0, lq, bufA);
    int t = t0;
    while (t < t1) {
        if (t + 1 < t1) load_tile(fb0, fb1, atlas, t + 1, lq, bufB);   // prefetch
        compute_tile(bufA, l15, acc);
        ++t;
        if (t >= t1) break;
        if (t + 1 < t1) load_tile(fb0, fb1, atlas, t + 1, lq, bufA);   // prefetch
        compute_tile(bufB, l15, acc);
        ++t;
    }

    // Epilogue: D row = lq*4 + r (ch within 16), col = l15 (seg). Waves own disjoint rows.
    float* p = part + (use_atomic ? 0 : (size_t)bx * BIN_SZ);
    #pragma unroll
    for (int a = 0; a < 2; ++a)
        #pragma unroll
        for (int sb = 0; sb < 6; ++sb)
            #pragma unroll
            for (int r = 0; r < 4; ++r) {
                const int i = (wv * 32 + a * 16 + lq * 4 + r) * PSEG + sb * 16 + l15;
                if (use_atomic) unsafeAtomicAdd(&p[i], acc[a][sb][r]);
                else            p[i] = acc[a][sb][r];
            }
}

// Deterministic seg counts: per-block LDS histogram -> private slot (no global atomics, no zeroing).
__global__ __launch_bounds__(256) void seg_count(const int* __restrict__ atlas,
                                                 int* __restrict__ cslot)
{
    __shared__ int cbin[PSEG];
    const int tid = threadIdx.x;
    if (tid < PSEG) cbin[tid] = 0;
    __syncthreads();
    for (int i = blockIdx.x * 256 + tid; i < NVOX; i += NCB * 256)
        atomicAdd(&cbin[atlas[i]], 1);
    __syncthreads();
    if (tid < PSEG) cslot[blockIdx.x * PSEG + tid] = cbin[tid];
}

// Stage A: sum GRID partials down to NCHUNK, coalesced across elem.
__global__ __launch_bounds__(256) void reduce_stageA(const float* __restrict__ part,
                                                     float* __restrict__ part2)
{
    const int g = blockIdx.x * 256 + threadIdx.x;      // [0, BIN_SZ*NCHUNK)
    const int c = g / BIN_SZ, e = g - c * BIN_SZ;
    const float* p = part + (size_t)c * KPC * BIN_SZ + e;
    float s = 0.0f;
    #pragma unroll 8
    for (int k = 0; k < KPC; ++k) s += p[(size_t)k * BIN_SZ];
    part2[g] = s;
}

__global__ __launch_bounds__(256) void finalize(const float* __restrict__ src,
                                                const int*   __restrict__ cslot,
                                                float* __restrict__ out,
                                                int n)
{
    const int idx = blockIdx.x * 256 + threadIdx.x;
    if (idx >= OUT_N) return;
    const int c   = idx & 63;
    const int s0  = (idx >> 6) % 94;
    const int b   = idx / (94 * 64);
    const int seg = s0 + 1;
    const int ch  = b * 64 + c;
    float s = 0.0f;
    for (int k = 0; k < n; ++k)
        s += src[(size_t)k * BIN_SZ + ch * PSEG + seg];
    int cnt = 0;
    #pragma unroll 8
    for (int k = 0; k < NCB; ++k) cnt += cslot[k * PSEG + seg];
    out[idx] = s / fmaxf((float)cnt, 1e-6f);
}

extern "C" void kernel_launch(void* const* d_in, const int* in_sizes, int n_in,
                              void* d_out, int out_size, void* d_ws, size_t ws_size,
                              hipStream_t stream)
{
    const float* feat  = (const float*)d_in[0];
    const int*   atlas = (const int*)d_in[1];
    float* out  = (float*)d_out;
    float* part = (float*)d_ws;
    const int use_atomic = (ws_size < WS_NEED) ? 1 : 0;
    float* part2 = use_atomic ? part : (float*)((char*)d_ws + P2_OFF);
    int*   cslot = use_atomic ? (int*)((char*)d_ws + (size_t)BIN_SZ * sizeof(float))
                              : (int*)((char*)d_ws + CNT_OFF);

    if (use_atomic)
        zero_part<<<(BIN_SZ + 255) / 256, 256, 0, stream>>>(part);
    seg_count<<<NCB, 256, 0, stream>>>(atlas, cslot);
    seg_mfma<<<GRID, 256, 0, stream>>>(feat, atlas, part, use_atomic);
    if (!use_atomic)
        reduce_stageA<<<(BIN_SZ * NCHUNK) / 256, 256, 0, stream>>>(part, part2);
    finalize<<<(OUT_N + 255) / 256, 256, 0, stream>>>(part2, cslot, out,
                                                      use_atomic ? 1 : NCHUNK);
}

// Round 14
// 146.936 us; speedup vs baseline: 2.2755x; 2.2755x over previous
//
#include <hip/hip_runtime.h>

// ROI pooling 3D as one-hot MFMA GEMM (transposed): part[ch][seg] = sum_v feat[ch][v] * onehot[v][seg].
// R14 = R8 + 2-tile unrolled body (both tiles' loads issued up front; halves exposed load latency).
// No structs/helpers (R13's TileBuf& spilled to scratch); counts in a separate histogram kernel.
constexpr int CROP_D  = 91, CROP_H = 109, CROP_W = 91;
constexpr int NVOX    = CROP_D * CROP_H * CROP_W;     // 902629
constexpr int LINES   = CROP_D * CROP_H;              // 9919
constexpr int FEAT_W  = 96;
constexpr int FEAT_HW = 112 * 96;
constexpr int CSTRIDE = 96 * 112 * 96;                // per-(b,c) elements
constexpr int NTILE   = LINES * 3;                    // 29757 tiles of 32 voxels (exact)
constexpr int PSEG    = 96;                           // 95 segs + trash col
constexpr int BIN_SZ  = 128 * PSEG;                   // 12288 floats per partial [ch][seg]
constexpr int GRID    = 1024;                         // 4 blocks/CU
constexpr int NCHUNK  = 16;
constexpr int KPC     = GRID / NCHUNK;                // 64
constexpr int NCB     = 64;                           // count-histogram blocks
constexpr int OUT_N   = 2 * 94 * 64;
constexpr size_t P2_OFF  = (size_t)GRID * BIN_SZ * sizeof(float);
constexpr size_t CNT_OFF = P2_OFF + (size_t)NCHUNK * BIN_SZ * sizeof(float);
constexpr size_t WS_NEED = CNT_OFF + (size_t)NCB * PSEG * sizeof(int);

typedef __attribute__((ext_vector_type(8))) short bf16x8;
typedef __attribute__((ext_vector_type(4))) float f32x4;

__device__ inline unsigned int rne2(float a, float b) {   // 2x fp32 -> packed bf16 (RNE)
    unsigned int x = __float_as_uint(a), y = __float_as_uint(b);
    x = (x + 0x7FFFu + ((x >> 16) & 1u)) >> 16;
    y = (y + 0x7FFFu + ((y >> 16) & 1u)) & 0xFFFF0000u;
    return x | y;
}

// Textually R8's verified load/compute body; named float4s + static id[] only (no aggregates).
#define LOAD_TILE(P00, P01, P10, P11, ID, T)                                          \
    {                                                                                 \
        const int line = (T) / 3, w0 = ((T) - line * 3) * 32;                         \
        const int d = line / CROP_H, h = line - d * CROP_H;                           \
        const int lb = d * FEAT_HW + h * FEAT_W + w0 + lq * 8;                        \
        P00 = *(const float4*)(fb0 + lb);                                             \
        P01 = *(const float4*)(fb0 + lb + 4);                                         \
        P10 = *(const float4*)(fb1 + lb);                                             \
        P11 = *(const float4*)(fb1 + lb + 4);                                         \
        const int wq = w0 + lq * 8, ab = line * CROP_W + wq;                          \
        _Pragma("unroll")                                                             \
        for (int j = 0; j < 8; ++j) ID[j] = (wq + j < CROP_W) ? atlas[ab + j] : 95;   \
    }

#define COMP_TILE(P00, P01, P10, P11, ID)                                             \
    {                                                                                 \
        union { bf16x8 v; unsigned int u[4]; } A0, A1;                                \
        A0.u[0] = rne2(P00.x, P00.y); A0.u[1] = rne2(P00.z, P00.w);                   \
        A0.u[2] = rne2(P01.x, P01.y); A0.u[3] = rne2(P01.z, P01.w);                   \
        A1.u[0] = rne2(P10.x, P10.y); A1.u[1] = rne2(P10.z, P10.w);                   \
        A1.u[2] = rne2(P11.x, P11.y); A1.u[3] = rne2(P11.z, P11.w);                   \
        _Pragma("unroll")                                                             \
        for (int sb = 0; sb < 6; ++sb) {                                              \
            const int seg = sb * 16 + l15;                                            \
            union { bf16x8 v; unsigned int u[4]; } B;                                 \
            _Pragma("unroll")                                                         \
            for (int p = 0; p < 4; ++p) {                                             \
                const unsigned int lo = (ID[2 * p]     == seg) ? 0x3F80u     : 0u;    \
                const unsigned int hi = (ID[2 * p + 1] == seg) ? 0x3F800000u : 0u;    \
                B.u[p] = lo | hi;                                                     \
            }                                                                         \
            acc[0][sb] = __builtin_amdgcn_mfma_f32_16x16x32_bf16(A0.v, B.v, acc[0][sb], 0, 0, 0); \
            acc[1][sb] = __builtin_amdgcn_mfma_f32_16x16x32_bf16(A1.v, B.v, acc[1][sb], 0, 0, 0); \
        }                                                                             \
    }

__global__ __launch_bounds__(256) void zero_part(float* __restrict__ p)   // atomic-fallback only
{
    const int i = blockIdx.x * 256 + threadIdx.x;
    if (i < BIN_SZ) p[i] = 0.0f;
}

__global__ __launch_bounds__(256, 4) void seg_mfma(const float* __restrict__ feat,
                                                   const int*   __restrict__ atlas,
                                                   float* __restrict__ part,
                                                   int use_atomic)
{
    const int tid = threadIdx.x, wv = tid >> 6, lane = tid & 63;
    const int l15 = lane & 15, lq = lane >> 4;

    f32x4 acc[2][6];                                   // 48 VGPR
    #pragma unroll
    for (int s = 0; s < 6; ++s) {
        acc[0][s] = (f32x4){0.f, 0.f, 0.f, 0.f};
        acc[1][s] = (f32x4){0.f, 0.f, 0.f, 0.f};
    }

    const int base = NTILE / GRID, rem = NTILE % GRID; // 29, 61
    const int bx   = blockIdx.x;
    const int t0   = bx * base + (bx < rem ? bx : rem);
    const int t1   = t0 + base + (bx < rem ? 1 : 0);

    const float* fb0 = feat + (size_t)(wv * 32 + l15) * CSTRIDE;        // a=0 subtile
    const float* fb1 = feat + (size_t)(wv * 32 + 16 + l15) * CSTRIDE;   // a=1 subtile

    float4 xp00, xp01, xp10, xp11; int xid[8];         // tile A buffer
    float4 yp00, yp01, yp10, yp11; int yid[8];         // tile B buffer

    int t = t0;
    for (; t + 1 < t1; t += 2) {                       // both tiles' loads issue before compute
        LOAD_TILE(xp00, xp01, xp10, xp11, xid, t)
        LOAD_TILE(yp00, yp01, yp10, yp11, yid, t + 1)
        COMP_TILE(xp00, xp01, xp10, xp11, xid)
        COMP_TILE(yp00, yp01, yp10, yp11, yid)
    }
    if (t < t1) {                                      // odd tail
        LOAD_TILE(xp00, xp01, xp10, xp11, xid, t)
        COMP_TILE(xp00, xp01, xp10, xp11, xid)
    }

    // Epilogue: D row = lq*4 + r (ch within 16), col = l15 (seg). Waves own disjoint rows.
    float* p = part + (use_atomic ? 0 : (size_t)bx * BIN_SZ);
    #pragma unroll
    for (int a = 0; a < 2; ++a)
        #pragma unroll
        for (int sb = 0; sb < 6; ++sb)
            #pragma unroll
            for (int r = 0; r < 4; ++r) {
                const int i = (wv * 32 + a * 16 + lq * 4 + r) * PSEG + sb * 16 + l15;
                if (use_atomic) unsafeAtomicAdd(&p[i], acc[a][sb][r]);
                else            p[i] = acc[a][sb][r];
            }
}

// Deterministic seg counts: per-block LDS histogram -> private slot (no global atomics, no zeroing).
__global__ __launch_bounds__(256) void seg_count(const int* __restrict__ atlas,
                                                 int* __restrict__ cslot)
{
    __shared__ int cbin[PSEG];
    const int tid = threadIdx.x;
    if (tid < PSEG) cbin[tid] = 0;
    __syncthreads();
    for (int i = blockIdx.x * 256 + tid; i < NVOX; i += NCB * 256)
        atomicAdd(&cbin[atlas[i]], 1);
    __syncthreads();
    if (tid < PSEG) cslot[blockIdx.x * PSEG + tid] = cbin[tid];
}

// Stage A: sum GRID partials down to NCHUNK, coalesced across elem.
__global__ __launch_bounds__(256) void reduce_stageA(const float* __restrict__ part,
                                                     float* __restrict__ part2)
{
    const int g = blockIdx.x * 256 + threadIdx.x;      // [0, BIN_SZ*NCHUNK)
    const int c = g / BIN_SZ, e = g - c * BIN_SZ;
    const float* p = part + (size_t)c * KPC * BIN_SZ + e;
    float s = 0.0f;
    #pragma unroll 8
    for (int k = 0; k < KPC; ++k) s += p[(size_t)k * BIN_SZ];
    part2[g] = s;
}

__global__ __launch_bounds__(256) void finalize(const float* __restrict__ src,
                                                const int*   __restrict__ cslot,
                                                float* __restrict__ out,
                                                int n)
{
    const int idx = blockIdx.x * 256 + threadIdx.x;
    if (idx >= OUT_N) return;
    const int c   = idx & 63;
    const int s0  = (idx >> 6) % 94;
    const int b   = idx / (94 * 64);
    const int seg = s0 + 1;
    const int ch  = b * 64 + c;
    float s = 0.0f;
    for (int k = 0; k < n; ++k)
        s += src[(size_t)k * BIN_SZ + ch * PSEG + seg];
    int cnt = 0;
    #pragma unroll 8
    for (int k = 0; k < NCB; ++k) cnt += cslot[k * PSEG + seg];
    out[idx] = s / fmaxf((float)cnt, 1e-6f);
}

extern "C" void kernel_launch(void* const* d_in, const int* in_sizes, int n_in,
                              void* d_out, int out_size, void* d_ws, size_t ws_size,
                              hipStream_t stream)
{
    const float* feat  = (const float*)d_in[0];
    const int*   atlas = (const int*)d_in[1];
    float* out  = (float*)d_out;
    float* part = (float*)d_ws;
    const int use_atomic = (ws_size < WS_NEED) ? 1 : 0;
    float* part2 = use_atomic ? part : (float*)((char*)d_ws + P2_OFF);
    int*   cslot = use_atomic ? (int*)((char*)d_ws + (size_t)BIN_SZ * sizeof(float))
                              : (int*)((char*)d_ws + CNT_OFF);

    if (use_atomic)
        zero_part<<<(BIN_SZ + 255) / 256, 256, 0, stream>>>(part);
    seg_count<<<NCB, 256, 0, stream>>>(atlas, cslot);
    seg_mfma<<<GRID, 256, 0, stream>>>(feat, atlas, part, use_atomic);
    if (!use_atomic)
        reduce_stageA<<<(BIN_SZ * NCHUNK) / 256, 256, 0, stream>>>(part, part2);
    finalize<<<(OUT_N + 255) / 256, 256, 0, stream>>>(part2, cslot, out,
                                                      use_atomic ? 1 : NCHUNK);
}

// Round 15
// 137.109 us; speedup vs baseline: 2.4386x; 1.0717x over previous
//
#include <hip/hip_runtime.h>

// ROI pooling 3D as one-hot MFMA GEMM (transposed): part[ch][seg] = sum_v feat[ch][v] * onehot[v][seg].
// Counts fused as row 128 via ones-vector GEMM (wave 0 only). No LDS, no atomics, deterministic tree.
// R15 = R8 verbatim (best verified config: 133.7 us). R9-R14 probed occupancy, LDS staging, DRAM
// burst length, SW pipelining, 2-tile unroll: all null or spill-regressed. Converged.
constexpr int SEG_N   = 95;
constexpr int CROP_D  = 91, CROP_H = 109, CROP_W = 91;
constexpr int LINES   = CROP_D * CROP_H;              // 9919
constexpr int FEAT_W  = 96;
constexpr int FEAT_HW = 112 * 96;
constexpr int CSTRIDE = 96 * 112 * 96;                // per-(b,c) elements
constexpr int NTILE   = LINES * 3;                    // 29757 tiles of 32 voxels (exact)
constexpr int PSEG    = 96;                           // 95 segs + trash col 95
constexpr int ROWS    = 129;                          // 128 ch + counts row
constexpr int BIN_SZ  = ROWS * PSEG;                  // 12384 floats per partial
constexpr int GRID    = 1024;                         // 4 blocks/CU
constexpr int NCHUNK  = 16;
constexpr int KPC     = GRID / NCHUNK;                // 64
constexpr int OUT_N   = 2 * 94 * 64;
constexpr size_t PART2_OFF = (size_t)GRID * BIN_SZ * sizeof(float);
constexpr size_t WS_NEED   = PART2_OFF + (size_t)NCHUNK * BIN_SZ * sizeof(float);

typedef __attribute__((ext_vector_type(8))) short bf16x8;
typedef __attribute__((ext_vector_type(4))) float f32x4;

__device__ inline unsigned int rne2(float a, float b) {   // 2x fp32 -> packed bf16 (RNE)
    unsigned int x = __float_as_uint(a), y = __float_as_uint(b);
    x = (x + 0x7FFFu + ((x >> 16) & 1u)) >> 16;
    y = (y + 0x7FFFu + ((y >> 16) & 1u)) & 0xFFFF0000u;
    return x | y;
}

__global__ __launch_bounds__(256) void zero_part(float* __restrict__ p)   // atomic-fallback only
{
    const int i = blockIdx.x * 256 + threadIdx.x;
    if (i < BIN_SZ) p[i] = 0.0f;
}

__global__ __launch_bounds__(256, 4) void seg_mfma(const float* __restrict__ feat,
                                                   const int*   __restrict__ atlas,
                                                   float* __restrict__ part,
                                                   int use_atomic)
{
    const int tid = threadIdx.x, wv = tid >> 6, lane = tid & 63;
    const int l15 = lane & 15, lq = lane >> 4;

    f32x4 acc[2][6];                                   // [ch-subtile][seg-tile]
    f32x4 accc[6];                                     // counts (live on wave 0 only)
    #pragma unroll
    for (int s = 0; s < 6; ++s) {
        acc[0][s] = (f32x4){0.f, 0.f, 0.f, 0.f};
        acc[1][s] = (f32x4){0.f, 0.f, 0.f, 0.f};
        accc[s]   = (f32x4){0.f, 0.f, 0.f, 0.f};
    }
    union { bf16x8 v; unsigned int u[4]; } ONES;
    ONES.u[0] = ONES.u[1] = ONES.u[2] = ONES.u[3] = 0x3F803F80u;

    // Contiguous balanced chunk per block: DRAM streams advance sequentially.
    const int base = NTILE / GRID, rem = NTILE % GRID;            // 29, 61
    const int bx   = blockIdx.x;
    const int t0   = bx * base + (bx < rem ? bx : rem);
    const int te   = t0 + base + (bx < rem ? 1 : 0);

    for (int t = t0; t < te; ++t) {
        const int line  = t / 3;                       // tile = 32 voxels inside one 96-wide line
        const int w0    = (t - line * 3) * 32;
        const int d     = line / CROP_H, h = line - d * CROP_H;
        const int lbase = d * FEAT_HW + h * FEAT_W + w0;

        // atlas ids for this lane's k-quarter: k = lq*8 + j (w >= 91 -> trash seg 95)
        int id[8];
        const int wq = w0 + lq * 8, abase = line * CROP_W + w0 + lq * 8;
        #pragma unroll
        for (int j = 0; j < 8; ++j)
            id[j] = (wq + j < CROP_W) ? atlas[abase + j] : 95;

        // B one-hot fragments per seg-tile: col = l15 (seg), k = lq*8 + j
        bf16x8 bv[6];
        #pragma unroll
        for (int sb = 0; sb < 6; ++sb) {
            const int seg = sb * 16 + l15;
            union { bf16x8 v; unsigned int u[4]; } B;
            #pragma unroll
            for (int p = 0; p < 4; ++p) {
                const unsigned int lo = (id[2 * p]     == seg) ? 0x3F80u     : 0u;
                const unsigned int hi = (id[2 * p + 1] == seg) ? 0x3F800000u : 0u;
                B.u[p] = lo | hi;
            }
            bv[sb] = B.v;
        }

        // counts: D = ones * onehot (all D rows identical = per-seg tile count)
        if (wv == 0) {
            #pragma unroll
            for (int sb = 0; sb < 6; ++sb)
                accc[sb] = __builtin_amdgcn_mfma_f32_16x16x32_bf16(ONES.v, bv[sb], accc[sb], 0, 0, 0);
        }

        // A fragments: row = l15 -> ch, k = lq*8 + j. One full 128B line per (ch, tile).
        #pragma unroll
        for (int a = 0; a < 2; ++a) {
            const int ch = wv * 32 + a * 16 + l15;
            const float* fp = feat + (size_t)ch * CSTRIDE + lbase + lq * 8;
            const float4 v0 = *(const float4*)fp;
            const float4 v1 = *(const float4*)(fp + 4);
            union { bf16x8 v; unsigned int u[4]; } A;
            A.u[0] = rne2(v0.x, v0.y); A.u[1] = rne2(v0.z, v0.w);
            A.u[2] = rne2(v1.x, v1.y); A.u[3] = rne2(v1.z, v1.w);
            #pragma unroll
            for (int sb = 0; sb < 6; ++sb)
                acc[a][sb] = __builtin_amdgcn_mfma_f32_16x16x32_bf16(A.v, bv[sb], acc[a][sb], 0, 0, 0);
        }
    }

    // Epilogue: D row = lq*4 + r (ch within 16), col = l15 (seg). Waves own disjoint rows.
    float* p = part + (use_atomic ? 0 : (size_t)blockIdx.x * BIN_SZ);
    #pragma unroll
    for (int a = 0; a < 2; ++a)
        #pragma unroll
        for (int sb = 0; sb < 6; ++sb)
            #pragma unroll
            for (int r = 0; r < 4; ++r) {
                const int i = (wv * 32 + a * 16 + lq * 4 + r) * PSEG + sb * 16 + l15;
                if (use_atomic) unsafeAtomicAdd(&p[i], acc[a][sb][r]);
                else            p[i] = acc[a][sb][r];
            }
    if (wv == 0 && lq == 0) {                          // counts row (any D row; take reg 0)
        #pragma unroll
        for (int sb = 0; sb < 6; ++sb) {
            const int i = 128 * PSEG + sb * 16 + l15;
            if (use_atomic) unsafeAtomicAdd(&p[i], accc[sb][0]);
            else            p[i] = accc[sb][0];
        }
    }
}

// Stage A: sum GRID partials down to NCHUNK, coalesced across elem.
__global__ __launch_bounds__(256) void reduce_stageA(const float* __restrict__ part,
                                                     float* __restrict__ part2)
{
    const int g = blockIdx.x * 256 + threadIdx.x;     // [0, BIN_SZ*NCHUNK)
    const int c = g / BIN_SZ, e = g - c * BIN_SZ;
    const float* p = part + (size_t)c * KPC * BIN_SZ + e;
    float s = 0.0f;
    #pragma unroll 8
    for (int k = 0; k < KPC; ++k) s += p[(size_t)k * BIN_SZ];
    part2[g] = s;
}

__global__ __launch_bounds__(256) void finalize(const float* __restrict__ src,
                                                float* __restrict__ out,
                                                int n)
{
    const int idx = blockIdx.x * 256 + threadIdx.x;
    if (idx >= OUT_N) return;
    const int c   = idx & 63;
    const int s0  = (idx >> 6) % 94;
    const int b   = idx / (94 * 64);
    const int seg = s0 + 1;
    const int ch  = b * 64 + c;
    float s = 0.0f, cnt = 0.0f;
    for (int k = 0; k < n; ++k) {
        s   += src[(size_t)k * BIN_SZ + ch * PSEG + seg];
        cnt += src[(size_t)k * BIN_SZ + 128 * PSEG + seg];
    }
    out[idx] = s / fmaxf(cnt, 1e-6f);
}

extern "C" void kernel_launch(void* const* d_in, const int* in_sizes, int n_in,
                              void* d_out, int out_size, void* d_ws, size_t ws_size,
                              hipStream_t stream)
{
    const float* feat  = (const float*)d_in[0];
    const int*   atlas = (const int*)d_in[1];
    float* out   = (float*)d_out;
    float* part  = (float*)d_ws;
    float* part2 = (float*)((char*)d_ws + PART2_OFF);
    const int use_atomic = (ws_size < WS_NEED) ? 1 : 0;

    if (use_atomic)
        zero_part<<<(BIN_SZ + 255) / 256, 256, 0, stream>>>(part);
    seg_mfma<<<GRID, 256, 0, stream>>>(feat, atlas, part, use_atomic);
    if (!use_atomic)
        reduce_stageA<<<(BIN_SZ * NCHUNK) / 256, 256, 0, stream>>>(part, part2);
    finalize<<<(OUT_N + 255) / 256, 256, 0, stream>>>(use_atomic ? part : part2, out,
                                                      use_atomic ? 1 : NCHUNK);
}